// Round 16
// baseline (64.639 us; speedup 1.0000x reference)
//
#include <hip/hip_runtime.h>
#include <hip/hip_fp16.h>

#define RDIM 1152
#define CIN  8
#define COUT 16
#define CDIM 10
#define BDIM 256
#define EPS 1e-7f

// ======================= Kernel A: u_hat producer =======================
// R16: traffic reduction. Block = (cg: 5 c's, 16-row chunk, 32-batch chunk).
// x chunk staged once in LDS, reused across 5 c's (x traffic 94->18.8 MB);
// ABB=32 doubles W reuse (94->47 MB). Total A traffic 280->158 MB -- every
// prior round kept ~280 MB invariant and all landed ~40 us (~7 TB/s fabric
// ceiling). W slice asm-pinned per c-iteration (R9); canonical uh layout;
// 16-B dwordx4 stores (R14).
#define ARB 16                   // rows per block
#define ABB 32                   // batches per block
#define NRBLK (RDIM / ARB)       // 72
#define NBBLK (BDIM / ABB)       // 8
#define NCG   2                  // c-groups (5 c's each)
#define ANWG (NRBLK * NBBLK * NCG)    // 1152 = 8*144
#define XSTRIDE 12               // dwords per LDS x row (8 + 4 pad)

__global__ __launch_bounds__(256) void caps_uhat(
    const float* __restrict__ x, const float* __restrict__ W,
    __half* __restrict__ uh)
{
    // XCD swizzle; cg innermost so the 2 blocks sharing an x-chunk are
    // adjacent (same XCD -> x L2 reuse).
    const int orig = blockIdx.x;
    const int id   = (orig & 7) * (ANWG / 8) + (orig >> 3);
    const int cg   = id & 1;
    const int rem  = id >> 1;
    const int bblk = rem & 7;            // 0..7
    const int rblk = rem >> 3;           // 0..71
    const int r0   = rblk * ARB;
    const int b0   = bblk * ABB;

    const int t  = threadIdx.x;
    const int u  = t & 31;
    const int rl = u >> 1;               // 0..15 row-in-chunk
    const int oh = u & 1;                // o-half
    const int bg = t >> 5;               // 0..7 batch group (4 batches each)

    __shared__ float xs[ABB * ARB * XSTRIDE];   // 24,576 B

    // ---- stage x chunk once: 32 batches x 16 rows x 32 B, coalesced ----
    {
        #pragma unroll
        for (int k = 0; k < 4; ++k) {
            const int unit = t + k * 256;    // 0..1023 16-B units
            const int bl   = unit >> 5;      // batch 0..31
            const int q    = unit & 31;      // 16-B chunk in 512-B row span
            float4 v = *(const float4*)(
                x + ((size_t)(b0 + bl) * RDIM + r0) * CIN + q * 4);
            *(float4*)&xs[(bl * ARB + (q >> 1)) * XSTRIDE + (q & 1) * 4] = v;
        }
    }
    __syncthreads();

    const size_t ustep = (size_t)RDIM * COUT;

    #pragma unroll 1
    for (int ci = 0; ci < 5; ++ci) {
        const int c = cg * 5 + ci;

        // ---- W slice (8 in x 8 out = 64 floats) direct from global, PIN ----
        float w0[8], w1[8], w2[8], w3[8], w4[8], w5[8], w6[8], w7[8];
        {
            const float* wb = W + ((size_t)c * RDIM + r0 + rl) * (CIN * COUT)
                            + oh * 8;
            #define LDW(I, DST)                                               \
            {                                                                 \
                float4 lo = *(const float4*)(wb + (I) * COUT);                \
                float4 hi = *(const float4*)(wb + (I) * COUT + 4);            \
                DST[0] = lo.x; DST[1] = lo.y; DST[2] = lo.z; DST[3] = lo.w;   \
                DST[4] = hi.x; DST[5] = hi.y; DST[6] = hi.z; DST[7] = hi.w;   \
            }
            LDW(0, w0) LDW(1, w1) LDW(2, w2) LDW(3, w3)
            LDW(4, w4) LDW(5, w5) LDW(6, w6) LDW(7, w7)
            #undef LDW
        }
        asm volatile("" :
            "+v"(w0[0]), "+v"(w0[1]), "+v"(w0[2]), "+v"(w0[3]),
            "+v"(w0[4]), "+v"(w0[5]), "+v"(w0[6]), "+v"(w0[7]),
            "+v"(w1[0]), "+v"(w1[1]), "+v"(w1[2]), "+v"(w1[3]),
            "+v"(w1[4]), "+v"(w1[5]), "+v"(w1[6]), "+v"(w1[7]));
        asm volatile("" :
            "+v"(w2[0]), "+v"(w2[1]), "+v"(w2[2]), "+v"(w2[3]),
            "+v"(w2[4]), "+v"(w2[5]), "+v"(w2[6]), "+v"(w2[7]),
            "+v"(w3[0]), "+v"(w3[1]), "+v"(w3[2]), "+v"(w3[3]),
            "+v"(w3[4]), "+v"(w3[5]), "+v"(w3[6]), "+v"(w3[7]));
        asm volatile("" :
            "+v"(w4[0]), "+v"(w4[1]), "+v"(w4[2]), "+v"(w4[3]),
            "+v"(w4[4]), "+v"(w4[5]), "+v"(w4[6]), "+v"(w4[7]),
            "+v"(w5[0]), "+v"(w5[1]), "+v"(w5[2]), "+v"(w5[3]),
            "+v"(w5[4]), "+v"(w5[5]), "+v"(w5[6]), "+v"(w5[7]));
        asm volatile("" :
            "+v"(w6[0]), "+v"(w6[1]), "+v"(w6[2]), "+v"(w6[3]),
            "+v"(w6[4]), "+v"(w6[5]), "+v"(w6[6]), "+v"(w6[7]),
            "+v"(w7[0]), "+v"(w7[1]), "+v"(w7[2]), "+v"(w7[3]),
            "+v"(w7[4]), "+v"(w7[5]), "+v"(w7[6]), "+v"(w7[7]));

        __half* ubase = uh + (((size_t)c * BDIM + b0) * RDIM + r0 + rl) * COUT
                      + oh * 8;

        #pragma unroll
        for (int j = 0; j < 4; ++j) {
            const int bl = bg * 4 + j;
            const float* xp = &xs[(bl * ARB + rl) * XSTRIDE];
            float4 p0 = *(const float4*)(xp);
            float4 p1 = *(const float4*)(xp + 4);

            float a0 = p0.x * w0[0];
            float a1 = p0.x * w0[1];
            float a2 = p0.x * w0[2];
            float a3 = p0.x * w0[3];
            float a4 = p0.x * w0[4];
            float a5 = p0.x * w0[5];
            float a6 = p0.x * w0[6];
            float a7 = p0.x * w0[7];
            #define FMA8(XI, WR)                                              \
                a0 = fmaf((XI), WR[0], a0); a1 = fmaf((XI), WR[1], a1);       \
                a2 = fmaf((XI), WR[2], a2); a3 = fmaf((XI), WR[3], a3);       \
                a4 = fmaf((XI), WR[4], a4); a5 = fmaf((XI), WR[5], a5);       \
                a6 = fmaf((XI), WR[6], a6); a7 = fmaf((XI), WR[7], a7);
            FMA8(p0.y, w1) FMA8(p0.z, w2) FMA8(p0.w, w3)
            FMA8(p1.x, w4) FMA8(p1.y, w5) FMA8(p1.z, w6) FMA8(p1.w, w7)
            #undef FMA8

            __half2 h0 = __floats2half2_rn(a0, a1), h1 = __floats2half2_rn(a2, a3);
            __half2 h2 = __floats2half2_rn(a4, a5), h3 = __floats2half2_rn(a6, a7);
            uint4 packed = make_uint4(
                *(const unsigned*)&h0, *(const unsigned*)&h1,
                *(const unsigned*)&h2, *(const unsigned*)&h3);
            *(uint4*)(ubase + (size_t)bl * ustep) = packed;   // dwordx4
        }
    }
}

// ======================= Kernel B: routing (R14 canonical, proven) =======================
#define BUNIT 18                 // quarter-rows per thread: 1152*4/256

__global__ __launch_bounds__(256) void caps_route2(
    const __half* __restrict__ uh, float* __restrict__ out)
{
    const int cb   = blockIdx.x;         // c*256 + b
    const int t    = threadIdx.x;
    const int lane = t & 63;
    const int wave = t >> 6;
    const int oq   = t & 3;
    const int rsub = t >> 2;             // 0..63

    __shared__ uint2 uhs[RDIM * COUT / 4];   // 36,864 B, [r*4 + oq]
    __shared__ float red[4][20];
    __shared__ __align__(16) float vout[COUT];

    // ---- stage slab + iteration-0 sum (c = 1/1152 uniform, no exp) ----
    const uint4* src = (const uint4*)(uh + (size_t)cb * RDIM * COUT);
    uint4* dst = (uint4*)uhs;
    float sp[8] = {0.f, 0.f, 0.f, 0.f, 0.f, 0.f, 0.f, 0.f};
    #pragma unroll
    for (int k = 0; k < 9; ++k) {
        uint4 v = src[t + k * 256];      // 8 halves
        dst[t + k * 256] = v;
        float2 f0 = __half22float2(*(const __half2*)&v.x);
        float2 f1 = __half22float2(*(const __half2*)&v.y);
        float2 f2 = __half22float2(*(const __half2*)&v.z);
        float2 f3 = __half22float2(*(const __half2*)&v.w);
        sp[0] += f0.x; sp[1] += f0.y; sp[2] += f1.x; sp[3] += f1.y;
        sp[4] += f2.x; sp[5] += f2.y; sp[6] += f3.x; sp[7] += f3.y;
    }
    #pragma unroll
    for (int off = 2; off <= 32; off <<= 1) {
        #pragma unroll
        for (int j = 0; j < 8; ++j) sp[j] += __shfl_xor(sp[j], off);
    }
    if (lane < 2) {
        #pragma unroll
        for (int j = 0; j < 8; ++j) red[wave][lane * 8 + j] = sp[j];
    }
    __syncthreads();

    if (wave == 0 && lane < COUT) {
        float s = 0.f;
        #pragma unroll
        for (int w2 = 0; w2 < 4; ++w2) s += red[w2][lane];
        s *= (1.0f / (float)RDIM);       // Z = 1152 exactly (e = exp(0))
        float sn = s * s;
        #pragma unroll
        for (int off = 1; off < 16; off <<= 1) sn += __shfl_xor(sn, off);
        const float scale = (sn / (1.0f + sn)) / sqrtf(sn + EPS);
        vout[lane] = s * scale;
    }
    __syncthreads();

    // ---- 2 combined passes: b += u.v_prev; e = exp(b); s += e*u ----
    float bb[BUNIT];
    #pragma unroll
    for (int k = 0; k < BUNIT; ++k) bb[k] = 0.f;

    #pragma unroll
    for (int it = 1; it <= 2; ++it) {
        const float4 vq = *(const float4*)&vout[oq * 4];
        float Zp = 0.f, s0 = 0.f, s1 = 0.f, s2 = 0.f, s3 = 0.f;
        #pragma unroll
        for (int k = 0; k < BUNIT; ++k) {
            const int r = k * 64 + rsub;
            uint2 raw = uhs[r * 4 + oq];
            float2 fA = __half22float2(*(const __half2*)&raw.x);
            float2 fB = __half22float2(*(const __half2*)&raw.y);
            float a = fA.x * vq.x;
            a = fmaf(fA.y, vq.y, a);
            a = fmaf(fB.x, vq.z, a);
            a = fmaf(fB.y, vq.w, a);
            a += __shfl_xor(a, 1);
            a += __shfl_xor(a, 2);
            bb[k] += a;
            float e = __expf(bb[k]);
            Zp += e;
            s0 = fmaf(e, fA.x, s0); s1 = fmaf(e, fA.y, s1);
            s2 = fmaf(e, fB.x, s2); s3 = fmaf(e, fB.y, s3);
        }
        #pragma unroll
        for (int off = 32; off >= 4; off >>= 1) {
            Zp += __shfl_xor(Zp, off);
            s0 += __shfl_xor(s0, off);
            s1 += __shfl_xor(s1, off);
            s2 += __shfl_xor(s2, off);
            s3 += __shfl_xor(s3, off);
        }
        if (lane < 4) {
            red[wave][lane * 4 + 0] = s0;
            red[wave][lane * 4 + 1] = s1;
            red[wave][lane * 4 + 2] = s2;
            red[wave][lane * 4 + 3] = s3;
            if (lane == 0) red[wave][16] = Zp;
        }
        __syncthreads();
        if (wave == 0 && lane < COUT) {
            float Z = 0.f;
            #pragma unroll
            for (int w2 = 0; w2 < 4; ++w2) Z += red[w2][16];
            float s = 0.f;
            #pragma unroll
            for (int w2 = 0; w2 < 4; ++w2) s += red[w2][lane];
            s /= Z;
            float sn = s * s;
            #pragma unroll
            for (int off = 1; off < 16; off <<= 1) sn += __shfl_xor(sn, off);
            const float scale = (sn / (1.0f + sn)) / sqrtf(sn + EPS);
            vout[lane] = s * scale;
        }
        __syncthreads();
    }

    if (t < 4) {
        float* op = out + (size_t)cb * COUT + t * 4;
        *(float4*)op = *(const float4*)&vout[t * 4];
    }
}

// ============== Fallback: proven R5 fused kernel (98 us) ==============
#define NB   2
#define FBLOCK 384
#define FUNITS 12
#define FNW (FBLOCK / 64)
#define NPAIR (BDIM / NB)
#define FNWG (CDIM * NPAIR)

__global__ __launch_bounds__(FBLOCK) void caps_route_fused(
    const float* __restrict__ x, const float* __restrict__ W,
    float* __restrict__ out)
{
    const int orig = blockIdx.x;
    const int wg   = (orig & 7) * (FNWG / 8) + (orig >> 3);
    const int c    = wg / NPAIR;
    const int b0   = (wg % NPAIR) * NB;
    const int tid  = threadIdx.x;
    const int lane = tid & 63;
    const int wave = tid >> 6;
    const int oq   = tid & 3;
    const int rsub = tid >> 2;

    __shared__ uint2 uhT[NB][4][1156];
    __shared__ float red[NB][FNW][COUT];
    __shared__ float scalz[NB][FNW];
    __shared__ __align__(16) float vout[NB][COUT];

    const float* __restrict__ Wc  = W + (size_t)c * RDIM * CIN * COUT;
    const float* __restrict__ xb0 = x + (size_t)b0 * RDIM * CIN;
    const float* __restrict__ xb1 = xb0 + RDIM * CIN;

    #pragma unroll
    for (int k = 0; k < FUNITS; ++k) {
        const int r = k * 96 + rsub;
        const float4* xq0 = (const float4*)(xb0 + (size_t)r * CIN);
        const float4* xq1 = (const float4*)(xb1 + (size_t)r * CIN);
        float4 p00 = xq0[0], p01 = xq0[1];
        float4 p10 = xq1[0], p11 = xq1[1];
        float xr0[CIN] = {p00.x, p00.y, p00.z, p00.w, p01.x, p01.y, p01.z, p01.w};
        float xr1[CIN] = {p10.x, p10.y, p10.z, p10.w, p11.x, p11.y, p11.z, p11.w};
        const float* wrow = Wc + (size_t)r * (CIN * COUT) + oq * 4;
        float a00 = 0.f, a01 = 0.f, a02 = 0.f, a03 = 0.f;
        float a10 = 0.f, a11 = 0.f, a12 = 0.f, a13 = 0.f;
        #pragma unroll
        for (int i = 0; i < CIN; ++i) {
            float4 w = *(const float4*)(wrow + i * COUT);
            a00 = fmaf(xr0[i], w.x, a00); a01 = fmaf(xr0[i], w.y, a01);
            a02 = fmaf(xr0[i], w.z, a02); a03 = fmaf(xr0[i], w.w, a03);
            a10 = fmaf(xr1[i], w.x, a10); a11 = fmaf(xr1[i], w.y, a11);
            a12 = fmaf(xr1[i], w.z, a12); a13 = fmaf(xr1[i], w.w, a13);
        }
        __half2 hA0 = __floats2half2_rn(a00, a01), hB0 = __floats2half2_rn(a02, a03);
        __half2 hA1 = __floats2half2_rn(a10, a11), hB1 = __floats2half2_rn(a12, a13);
        uhT[0][oq][r] = make_uint2(*(const unsigned*)&hA0, *(const unsigned*)&hB0);
        uhT[1][oq][r] = make_uint2(*(const unsigned*)&hA1, *(const unsigned*)&hB1);
    }
    __syncthreads();

    float bb0[FUNITS], bb1[FUNITS];
    #pragma unroll
    for (int k = 0; k < FUNITS; ++k) { bb0[k] = 0.f; bb1[k] = 0.f; }

    #pragma unroll
    for (int it = 0; it < 3; ++it) {
        float Zp0 = 0.f, s00 = 0.f, s01 = 0.f, s02 = 0.f, s03 = 0.f;
        float Zp1 = 0.f, s10 = 0.f, s11 = 0.f, s12 = 0.f, s13 = 0.f;
        #pragma unroll
        for (int k = 0; k < FUNITS; ++k) {
            const int r = k * 96 + rsub;
            float e0 = __expf(bb0[k]);
            float e1 = __expf(bb1[k]);
            uint2 r0 = uhT[0][oq][r], r1 = uhT[1][oq][r];
            float2 fA0 = __half22float2(*(const __half2*)&r0.x);
            float2 fB0 = __half22float2(*(const __half2*)&r0.y);
            float2 fA1 = __half22float2(*(const __half2*)&r1.x);
            float2 fB1 = __half22float2(*(const __half2*)&r1.y);
            Zp0 += e0; Zp1 += e1;
            s00 = fmaf(e0, fA0.x, s00); s01 = fmaf(e0, fA0.y, s01);
            s02 = fmaf(e0, fB0.x, s02); s03 = fmaf(e0, fB0.y, s03);
            s10 = fmaf(e1, fA1.x, s10); s11 = fmaf(e1, fA1.y, s11);
            s12 = fmaf(e1, fB1.x, s12); s13 = fmaf(e1, fB1.y, s13);
        }
        #pragma unroll
        for (int off = 32; off >= 4; off >>= 1) {
            Zp0 += __shfl_xor(Zp0, off);  Zp1 += __shfl_xor(Zp1, off);
            s00 += __shfl_xor(s00, off);  s10 += __shfl_xor(s10, off);
            s01 += __shfl_xor(s01, off);  s11 += __shfl_xor(s11, off);
            s02 += __shfl_xor(s02, off);  s12 += __shfl_xor(s12, off);
            s03 += __shfl_xor(s03, off);  s13 += __shfl_xor(s13, off);
        }
        if (lane < 4) {
            red[0][wave][lane * 4 + 0] = s00; red[0][wave][lane * 4 + 1] = s01;
            red[0][wave][lane * 4 + 2] = s02; red[0][wave][lane * 4 + 3] = s03;
            red[1][wave][lane * 4 + 0] = s10; red[1][wave][lane * 4 + 1] = s11;
            red[1][wave][lane * 4 + 2] = s12; red[1][wave][lane * 4 + 3] = s13;
            if (lane == 0) { scalz[0][wave] = Zp0; scalz[1][wave] = Zp1; }
        }
        __syncthreads();
        if (wave == 0 && (lane & 31) < COUT) {
            const int nb = lane >> 5;
            const int o  = lane & 15;
            float Z = 0.f;
            #pragma unroll
            for (int w2 = 0; w2 < FNW; ++w2) Z += scalz[nb][w2];
            float s = 0.f;
            #pragma unroll
            for (int w2 = 0; w2 < FNW; ++w2) s += red[nb][w2][o];
            s /= Z;
            float sn = s * s;
            #pragma unroll
            for (int off = 1; off < 16; off <<= 1) sn += __shfl_xor(sn, off);
            const float scale = (sn / (1.0f + sn)) / sqrtf(sn + EPS);
            vout[nb][o] = s * scale;
        }
        __syncthreads();
        if (it < 2) {
            const float4 v0 = *(const float4*)&vout[0][oq * 4];
            const float4 v1 = *(const float4*)&vout[1][oq * 4];
            #pragma unroll
            for (int k = 0; k < FUNITS; ++k) {
                const int r = k * 96 + rsub;
                uint2 r0 = uhT[0][oq][r], r1 = uhT[1][oq][r];
                float2 fA0 = __half22float2(*(const __half2*)&r0.x);
                float2 fB0 = __half22float2(*(const __half2*)&r0.y);
                float2 fA1 = __half22float2(*(const __half2*)&r1.x);
                float2 fB1 = __half22float2(*(const __half2*)&r1.y);
                float a0 = fA0.x * v0.x;
                a0 = fmaf(fA0.y, v0.y, a0);
                a0 = fmaf(fB0.x, v0.z, a0);
                a0 = fmaf(fB0.y, v0.w, a0);
                float a1 = fA1.x * v1.x;
                a1 = fmaf(fA1.y, v1.y, a1);
                a1 = fmaf(fB1.x, v1.z, a1);
                a1 = fmaf(fB1.y, v1.w, a1);
                a0 += __shfl_xor(a0, 1);  a1 += __shfl_xor(a1, 1);
                a0 += __shfl_xor(a0, 2);  a1 += __shfl_xor(a1, 2);
                bb0[k] += a0;
                bb1[k] += a1;
            }
        }
    }
    if (tid < 8) {
        const int nb = tid >> 2, q = tid & 3;
        float* op = out + ((size_t)c * BDIM + b0 + nb) * COUT + q * 4;
        *(float4*)op = *(const float4*)&vout[nb][q * 4];
    }
}

extern "C" void kernel_launch(void* const* d_in, const int* in_sizes, int n_in,
                              void* d_out, int out_size, void* d_ws, size_t ws_size,
                              hipStream_t stream) {
    const float* x = (const float*)d_in[0];   // [256,1152,8]
    const float* W = (const float*)d_in[1];   // [10,1152,8,16]
    float* out = (float*)d_out;               // [10,256,1,1,16]

    const size_t UH_BYTES = (size_t)CDIM * BDIM * RDIM * COUT * sizeof(__half);
    if (ws_size >= UH_BYTES) {
        __half* uh = (__half*)d_ws;
        caps_uhat<<<ANWG, 256, 0, stream>>>(x, W, uh);
        caps_route2<<<CDIM * BDIM, 256, 0, stream>>>(uh, out);
    } else {
        caps_route_fused<<<FNWG, FBLOCK, 0, stream>>>(x, W, out);
    }
}

// Round 17
// 54.488 us; speedup vs baseline: 1.1863x; 1.1863x over previous
//
#include <hip/hip_runtime.h>
#include <hip/hip_fp16.h>

#define RDIM 1152
#define CIN  8
#define COUT 16
#define CDIM 10
#define BDIM 256
#define EPS 1e-7f

// ======================= Kernel A: u_hat producer (R12, best measured) ==========
// block = (c, 64-row chunk, 16-batch chunk). W slice pinned in 32 VGPRs
// (asm barrier, R9); x chunk staged once in LDS coalesced & duplication-free
// (R12); canonical uh layout [c][b][r][o]; 8-B stores. 54.7 us total measured.
#define ARB 64                   // rows per block
#define ABB 16                   // batches per block
#define NRBLK (RDIM / ARB)       // 18
#define NBBLK (BDIM / ABB)       // 16
#define ANWG (CDIM * NRBLK * NBBLK)   // 2880 = 8*360
#define XSTRIDE 12               // dwords per LDS x row (8 + 4 pad; 16B-aligned)

__global__ __launch_bounds__(256) void caps_uhat(
    const float* __restrict__ x, const float* __restrict__ W,
    __half* __restrict__ uh)
{
    // XCD-aware bijective swizzle; c-innermost so the 10 blocks sharing an
    // x-chunk are contiguous on one XCD (x L2 reuse).
    const int orig = blockIdx.x;
    const int id   = (orig & 7) * (ANWG / 8) + (orig >> 3);
    const int c    = id % CDIM;
    const int chnk = id / CDIM;          // 0..287
    const int rblk = chnk >> 4;          // 0..17
    const int bblk = chnk & 15;          // 0..15
    const int r0   = rblk * ARB;
    const int b0   = bblk * ABB;

    const int t  = threadIdx.x;
    const int oq = t & 3;                // o-quad
    const int rl = t >> 2;               // 0..63 row-in-chunk

    __shared__ float xs[ABB * ARB * XSTRIDE];   // 49,152 B

    // ---- stage x chunk: 16 batches x 64 rows x 32 B, fully coalesced,
    //      each 16-B chunk loaded by exactly one lane (no duplication) ----
    {
        const float* xsrc = x + ((size_t)b0 * RDIM + r0) * CIN;
        #pragma unroll
        for (int k = 0; k < 8; ++k) {
            const int u  = t + k * 256;      // 0..2047 16-B units
            const int bl = u >> 7;           // batch
            const int q  = u & 127;          // 16-B chunk within batch (2KB)
            float4 v = *(const float4*)(xsrc + (size_t)bl * RDIM * CIN + q * 4);
            *(float4*)&xs[(bl * ARB + (q >> 1)) * XSTRIDE + (q & 1) * 4] = v;
        }
    }

    // ---- per-thread W slice direct from global, then PIN in VGPRs ----
    float w00, w01, w02, w03, w10, w11, w12, w13;
    float w20, w21, w22, w23, w30, w31, w32, w33;
    float w40, w41, w42, w43, w50, w51, w52, w53;
    float w60, w61, w62, w63, w70, w71, w72, w73;
    {
        const float* wb = W + ((size_t)c * RDIM + r0 + rl) * (CIN * COUT) + oq * 4;
        float4 t0 = *(const float4*)(wb + 0 * COUT);
        float4 t1 = *(const float4*)(wb + 1 * COUT);
        float4 t2 = *(const float4*)(wb + 2 * COUT);
        float4 t3 = *(const float4*)(wb + 3 * COUT);
        float4 t4 = *(const float4*)(wb + 4 * COUT);
        float4 t5 = *(const float4*)(wb + 5 * COUT);
        float4 t6 = *(const float4*)(wb + 6 * COUT);
        float4 t7 = *(const float4*)(wb + 7 * COUT);
        w00 = t0.x; w01 = t0.y; w02 = t0.z; w03 = t0.w;
        w10 = t1.x; w11 = t1.y; w12 = t1.z; w13 = t1.w;
        w20 = t2.x; w21 = t2.y; w22 = t2.z; w23 = t2.w;
        w30 = t3.x; w31 = t3.y; w32 = t3.z; w33 = t3.w;
        w40 = t4.x; w41 = t4.y; w42 = t4.z; w43 = t4.w;
        w50 = t5.x; w51 = t5.y; w52 = t5.z; w53 = t5.w;
        w60 = t6.x; w61 = t6.y; w62 = t6.z; w63 = t6.w;
        w70 = t7.x; w71 = t7.y; w72 = t7.z; w73 = t7.w;
    }
    asm volatile("" :
        "+v"(w00), "+v"(w01), "+v"(w02), "+v"(w03),
        "+v"(w10), "+v"(w11), "+v"(w12), "+v"(w13),
        "+v"(w20), "+v"(w21), "+v"(w22), "+v"(w23),
        "+v"(w30), "+v"(w31), "+v"(w32), "+v"(w33),
        "+v"(w40), "+v"(w41), "+v"(w42), "+v"(w43),
        "+v"(w50), "+v"(w51), "+v"(w52), "+v"(w53),
        "+v"(w60), "+v"(w61), "+v"(w62), "+v"(w63),
        "+v"(w70), "+v"(w71), "+v"(w72), "+v"(w73));

    __syncthreads();

    __half* ubase = uh + (((size_t)c * BDIM + b0) * RDIM + r0 + rl) * COUT + oq * 4;
    const size_t ustep = (size_t)RDIM * COUT;
    const float* xrow = &xs[rl * XSTRIDE];

    #pragma unroll
    for (int bl = 0; bl < ABB; ++bl) {
        const float* xp = xrow + bl * (ARB * XSTRIDE);
        float4 p0 = *(const float4*)(xp);       // 2-way max banks + oq broadcast
        float4 p1 = *(const float4*)(xp + 4);

        float a0 = p0.x * w00;
        float a1 = p0.x * w01;
        float a2 = p0.x * w02;
        float a3 = p0.x * w03;
        a0 = fmaf(p0.y, w10, a0); a1 = fmaf(p0.y, w11, a1);
        a2 = fmaf(p0.y, w12, a2); a3 = fmaf(p0.y, w13, a3);
        a0 = fmaf(p0.z, w20, a0); a1 = fmaf(p0.z, w21, a1);
        a2 = fmaf(p0.z, w22, a2); a3 = fmaf(p0.z, w23, a3);
        a0 = fmaf(p0.w, w30, a0); a1 = fmaf(p0.w, w31, a1);
        a2 = fmaf(p0.w, w32, a2); a3 = fmaf(p0.w, w33, a3);
        a0 = fmaf(p1.x, w40, a0); a1 = fmaf(p1.x, w41, a1);
        a2 = fmaf(p1.x, w42, a2); a3 = fmaf(p1.x, w43, a3);
        a0 = fmaf(p1.y, w50, a0); a1 = fmaf(p1.y, w51, a1);
        a2 = fmaf(p1.y, w52, a2); a3 = fmaf(p1.y, w53, a3);
        a0 = fmaf(p1.z, w60, a0); a1 = fmaf(p1.z, w61, a1);
        a2 = fmaf(p1.z, w62, a2); a3 = fmaf(p1.z, w63, a3);
        a0 = fmaf(p1.w, w70, a0); a1 = fmaf(p1.w, w71, a1);
        a2 = fmaf(p1.w, w72, a2); a3 = fmaf(p1.w, w73, a3);

        __half2 h0 = __floats2half2_rn(a0, a1), h1 = __floats2half2_rn(a2, a3);
        *(uint2*)(ubase + bl * ustep) =
            make_uint2(*(const unsigned*)&h0, *(const unsigned*)&h1);
    }
}

// ======================= Kernel B: routing (R12, proven) =======================
#define BUNIT 18                 // quarter-rows per thread: 1152*4/256

__global__ __launch_bounds__(256) void caps_route2(
    const __half* __restrict__ uh, float* __restrict__ out)
{
    const int cb   = blockIdx.x;         // c*256 + b
    const int t    = threadIdx.x;
    const int lane = t & 63;
    const int wave = t >> 6;
    const int oq   = t & 3;
    const int rsub = t >> 2;             // 0..63

    __shared__ uint2 uhs[RDIM * COUT / 4];   // 36,864 B, [r*4 + oq]
    __shared__ float red[4][20];
    __shared__ __align__(16) float vout[COUT];

    // ---- stage slab + iteration-0 sum (c = 1/1152 uniform, no exp) ----
    const uint4* src = (const uint4*)(uh + (size_t)cb * RDIM * COUT);
    uint4* dst = (uint4*)uhs;
    float sp[8] = {0.f, 0.f, 0.f, 0.f, 0.f, 0.f, 0.f, 0.f};
    #pragma unroll
    for (int k = 0; k < 9; ++k) {
        uint4 v = src[t + k * 256];      // 8 halves
        dst[t + k * 256] = v;
        float2 f0 = __half22float2(*(const __half2*)&v.x);
        float2 f1 = __half22float2(*(const __half2*)&v.y);
        float2 f2 = __half22float2(*(const __half2*)&v.z);
        float2 f3 = __half22float2(*(const __half2*)&v.w);
        sp[0] += f0.x; sp[1] += f0.y; sp[2] += f1.x; sp[3] += f1.y;
        sp[4] += f2.x; sp[5] += f2.y; sp[6] += f3.x; sp[7] += f3.y;
    }
    #pragma unroll
    for (int off = 2; off <= 32; off <<= 1) {
        #pragma unroll
        for (int j = 0; j < 8; ++j) sp[j] += __shfl_xor(sp[j], off);
    }
    if (lane < 2) {
        #pragma unroll
        for (int j = 0; j < 8; ++j) red[wave][lane * 8 + j] = sp[j];
    }
    __syncthreads();

    if (wave == 0 && lane < COUT) {
        float s = 0.f;
        #pragma unroll
        for (int w2 = 0; w2 < 4; ++w2) s += red[w2][lane];
        s *= (1.0f / (float)RDIM);       // Z = 1152 exactly (e = exp(0))
        float sn = s * s;
        #pragma unroll
        for (int off = 1; off < 16; off <<= 1) sn += __shfl_xor(sn, off);
        const float scale = (sn / (1.0f + sn)) / sqrtf(sn + EPS);
        vout[lane] = s * scale;
    }
    __syncthreads();

    // ---- 2 combined passes: b += u.v_prev; e = exp(b); s += e*u ----
    float bb[BUNIT];
    #pragma unroll
    for (int k = 0; k < BUNIT; ++k) bb[k] = 0.f;

    #pragma unroll
    for (int it = 1; it <= 2; ++it) {
        const float4 vq = *(const float4*)&vout[oq * 4];
        float Zp = 0.f, s0 = 0.f, s1 = 0.f, s2 = 0.f, s3 = 0.f;
        #pragma unroll
        for (int k = 0; k < BUNIT; ++k) {
            const int r = k * 64 + rsub;
            uint2 raw = uhs[r * 4 + oq];
            float2 fA = __half22float2(*(const __half2*)&raw.x);
            float2 fB = __half22float2(*(const __half2*)&raw.y);
            float a = fA.x * vq.x;
            a = fmaf(fA.y, vq.y, a);
            a = fmaf(fB.x, vq.z, a);
            a = fmaf(fB.y, vq.w, a);
            a += __shfl_xor(a, 1);
            a += __shfl_xor(a, 2);
            bb[k] += a;
            float e = __expf(bb[k]);
            Zp += e;
            s0 = fmaf(e, fA.x, s0); s1 = fmaf(e, fA.y, s1);
            s2 = fmaf(e, fB.x, s2); s3 = fmaf(e, fB.y, s3);
        }
        #pragma unroll
        for (int off = 32; off >= 4; off >>= 1) {
            Zp += __shfl_xor(Zp, off);
            s0 += __shfl_xor(s0, off);
            s1 += __shfl_xor(s1, off);
            s2 += __shfl_xor(s2, off);
            s3 += __shfl_xor(s3, off);
        }
        if (lane < 4) {
            red[wave][lane * 4 + 0] = s0;
            red[wave][lane * 4 + 1] = s1;
            red[wave][lane * 4 + 2] = s2;
            red[wave][lane * 4 + 3] = s3;
            if (lane == 0) red[wave][16] = Zp;
        }
        __syncthreads();
        if (wave == 0 && lane < COUT) {
            float Z = 0.f;
            #pragma unroll
            for (int w2 = 0; w2 < 4; ++w2) Z += red[w2][16];
            float s = 0.f;
            #pragma unroll
            for (int w2 = 0; w2 < 4; ++w2) s += red[w2][lane];
            s /= Z;
            float sn = s * s;
            #pragma unroll
            for (int off = 1; off < 16; off <<= 1) sn += __shfl_xor(sn, off);
            const float scale = (sn / (1.0f + sn)) / sqrtf(sn + EPS);
            vout[lane] = s * scale;
        }
        __syncthreads();
    }

    if (t < 4) {
        float* op = out + (size_t)cb * COUT + t * 4;
        *(float4*)op = *(const float4*)&vout[t * 4];
    }
}

// ============== Fallback: proven R5 fused kernel (98 us) ==============
#define NB   2
#define FBLOCK 384
#define FUNITS 12
#define FNW (FBLOCK / 64)
#define NPAIR (BDIM / NB)
#define FNWG (CDIM * NPAIR)

__global__ __launch_bounds__(FBLOCK) void caps_route_fused(
    const float* __restrict__ x, const float* __restrict__ W,
    float* __restrict__ out)
{
    const int orig = blockIdx.x;
    const int wg   = (orig & 7) * (FNWG / 8) + (orig >> 3);
    const int c    = wg / NPAIR;
    const int b0   = (wg % NPAIR) * NB;
    const int tid  = threadIdx.x;
    const int lane = tid & 63;
    const int wave = tid >> 6;
    const int oq   = tid & 3;
    const int rsub = tid >> 2;

    __shared__ uint2 uhT[NB][4][1156];
    __shared__ float red[NB][FNW][COUT];
    __shared__ float scalz[NB][FNW];
    __shared__ __align__(16) float vout[NB][COUT];

    const float* __restrict__ Wc  = W + (size_t)c * RDIM * CIN * COUT;
    const float* __restrict__ xb0 = x + (size_t)b0 * RDIM * CIN;
    const float* __restrict__ xb1 = xb0 + RDIM * CIN;

    #pragma unroll
    for (int k = 0; k < FUNITS; ++k) {
        const int r = k * 96 + rsub;
        const float4* xq0 = (const float4*)(xb0 + (size_t)r * CIN);
        const float4* xq1 = (const float4*)(xb1 + (size_t)r * CIN);
        float4 p00 = xq0[0], p01 = xq0[1];
        float4 p10 = xq1[0], p11 = xq1[1];
        float xr0[CIN] = {p00.x, p00.y, p00.z, p00.w, p01.x, p01.y, p01.z, p01.w};
        float xr1[CIN] = {p10.x, p10.y, p10.z, p10.w, p11.x, p11.y, p11.z, p11.w};
        const float* wrow = Wc + (size_t)r * (CIN * COUT) + oq * 4;
        float a00 = 0.f, a01 = 0.f, a02 = 0.f, a03 = 0.f;
        float a10 = 0.f, a11 = 0.f, a12 = 0.f, a13 = 0.f;
        #pragma unroll
        for (int i = 0; i < CIN; ++i) {
            float4 w = *(const float4*)(wrow + i * COUT);
            a00 = fmaf(xr0[i], w.x, a00); a01 = fmaf(xr0[i], w.y, a01);
            a02 = fmaf(xr0[i], w.z, a02); a03 = fmaf(xr0[i], w.w, a03);
            a10 = fmaf(xr1[i], w.x, a10); a11 = fmaf(xr1[i], w.y, a11);
            a12 = fmaf(xr1[i], w.z, a12); a13 = fmaf(xr1[i], w.w, a13);
        }
        __half2 hA0 = __floats2half2_rn(a00, a01), hB0 = __floats2half2_rn(a02, a03);
        __half2 hA1 = __floats2half2_rn(a10, a11), hB1 = __floats2half2_rn(a12, a13);
        uhT[0][oq][r] = make_uint2(*(const unsigned*)&hA0, *(const unsigned*)&hB0);
        uhT[1][oq][r] = make_uint2(*(const unsigned*)&hA1, *(const unsigned*)&hB1);
    }
    __syncthreads();

    float bb0[FUNITS], bb1[FUNITS];
    #pragma unroll
    for (int k = 0; k < FUNITS; ++k) { bb0[k] = 0.f; bb1[k] = 0.f; }

    #pragma unroll
    for (int it = 0; it < 3; ++it) {
        float Zp0 = 0.f, s00 = 0.f, s01 = 0.f, s02 = 0.f, s03 = 0.f;
        float Zp1 = 0.f, s10 = 0.f, s11 = 0.f, s12 = 0.f, s13 = 0.f;
        #pragma unroll
        for (int k = 0; k < FUNITS; ++k) {
            const int r = k * 96 + rsub;
            float e0 = __expf(bb0[k]);
            float e1 = __expf(bb1[k]);
            uint2 r0 = uhT[0][oq][r], r1 = uhT[1][oq][r];
            float2 fA0 = __half22float2(*(const __half2*)&r0.x);
            float2 fB0 = __half22float2(*(const __half2*)&r0.y);
            float2 fA1 = __half22float2(*(const __half2*)&r1.x);
            float2 fB1 = __half22float2(*(const __half2*)&r1.y);
            Zp0 += e0; Zp1 += e1;
            s00 = fmaf(e0, fA0.x, s00); s01 = fmaf(e0, fA0.y, s01);
            s02 = fmaf(e0, fB0.x, s02); s03 = fmaf(e0, fB0.y, s03);
            s10 = fmaf(e1, fA1.x, s10); s11 = fmaf(e1, fA1.y, s11);
            s12 = fmaf(e1, fB1.x, s12); s13 = fmaf(e1, fB1.y, s13);
        }
        #pragma unroll
        for (int off = 32; off >= 4; off >>= 1) {
            Zp0 += __shfl_xor(Zp0, off);  Zp1 += __shfl_xor(Zp1, off);
            s00 += __shfl_xor(s00, off);  s10 += __shfl_xor(s10, off);
            s01 += __shfl_xor(s01, off);  s11 += __shfl_xor(s11, off);
            s02 += __shfl_xor(s02, off);  s12 += __shfl_xor(s12, off);
            s03 += __shfl_xor(s03, off);  s13 += __shfl_xor(s13, off);
        }
        if (lane < 4) {
            red[0][wave][lane * 4 + 0] = s00; red[0][wave][lane * 4 + 1] = s01;
            red[0][wave][lane * 4 + 2] = s02; red[0][wave][lane * 4 + 3] = s03;
            red[1][wave][lane * 4 + 0] = s10; red[1][wave][lane * 4 + 1] = s11;
            red[1][wave][lane * 4 + 2] = s12; red[1][wave][lane * 4 + 3] = s13;
            if (lane == 0) { scalz[0][wave] = Zp0; scalz[1][wave] = Zp1; }
        }
        __syncthreads();
        if (wave == 0 && (lane & 31) < COUT) {
            const int nb = lane >> 5;
            const int o  = lane & 15;
            float Z = 0.f;
            #pragma unroll
            for (int w2 = 0; w2 < FNW; ++w2) Z += scalz[nb][w2];
            float s = 0.f;
            #pragma unroll
            for (int w2 = 0; w2 < FNW; ++w2) s += red[nb][w2][o];
            s /= Z;
            float sn = s * s;
            #pragma unroll
            for (int off = 1; off < 16; off <<= 1) sn += __shfl_xor(sn, off);
            const float scale = (sn / (1.0f + sn)) / sqrtf(sn + EPS);
            vout[nb][o] = s * scale;
        }
        __syncthreads();
        if (it < 2) {
            const float4 v0 = *(const float4*)&vout[0][oq * 4];
            const float4 v1 = *(const float4*)&vout[1][oq * 4];
            #pragma unroll
            for (int k = 0; k < FUNITS; ++k) {
                const int r = k * 96 + rsub;
                uint2 r0 = uhT[0][oq][r], r1 = uhT[1][oq][r];
                float2 fA0 = __half22float2(*(const __half2*)&r0.x);
                float2 fB0 = __half22float2(*(const __half2*)&r0.y);
                float2 fA1 = __half22float2(*(const __half2*)&r1.x);
                float2 fB1 = __half22float2(*(const __half2*)&r1.y);
                float a0 = fA0.x * v0.x;
                a0 = fmaf(fA0.y, v0.y, a0);
                a0 = fmaf(fB0.x, v0.z, a0);
                a0 = fmaf(fB0.y, v0.w, a0);
                float a1 = fA1.x * v1.x;
                a1 = fmaf(fA1.y, v1.y, a1);
                a1 = fmaf(fB1.x, v1.z, a1);
                a1 = fmaf(fB1.y, v1.w, a1);
                a0 += __shfl_xor(a0, 1);  a1 += __shfl_xor(a1, 1);
                a0 += __shfl_xor(a0, 2);  a1 += __shfl_xor(a1, 2);
                bb0[k] += a0;
                bb1[k] += a1;
            }
        }
    }
    if (tid < 8) {
        const int nb = tid >> 2, q = tid & 3;
        float* op = out + ((size_t)c * BDIM + b0 + nb) * COUT + q * 4;
        *(float4*)op = *(const float4*)&vout[nb][q * 4];
    }
}

extern "C" void kernel_launch(void* const* d_in, const int* in_sizes, int n_in,
                              void* d_out, int out_size, void* d_ws, size_t ws_size,
                              hipStream_t stream) {
    const float* x = (const float*)d_in[0];   // [256,1152,8]
    const float* W = (const float*)d_in[1];   // [10,1152,8,16]
    float* out = (float*)d_out;               // [10,256,1,1,16]

    const size_t UH_BYTES = (size_t)CDIM * BDIM * RDIM * COUT * sizeof(__half);
    if (ws_size >= UH_BYTES) {
        __half* uh = (__half*)d_ws;
        caps_uhat<<<ANWG, 256, 0, stream>>>(x, W, uh);
        caps_route2<<<CDIM * BDIM, 256, 0, stream>>>(uh, out);
    } else {
        caps_route_fused<<<FNWG, FBLOCK, 0, stream>>>(x, W, out);
    }
}